// Round 1
// baseline (698.479 us; speedup 1.0000x reference)
//
#include <hip/hip_runtime.h>
#include <float.h>

// Problem constants
#define N_TOK   32768      // B*H*W = 32*32*32
#define DIM     64
#define K_CODES 8192
#define BB      32
#define CC      64
#define HH      32
#define WW      32
#define HWSZ    1024       // H*W
#define CHW     65536      // C*H*W
#define NELEM   2097152    // B*C*H*W

// d_out layout (floats):
// [0, 2097152)                z_q_st (NCHW)
// [2097152]                   loss
// [2097153, +32768)           idx (as float)
// [2129921, +8192)            cs_norm        (doubles as cnt accumulator)
// [2138113, +524288)          ema_w_out
// [2662401, +524288)          emb_out        (doubles as new_ema_w accumulator)

// ---------------- K1: per-code squared norms ----------------
__global__ __launch_bounds__(256) void enorm_kernel(const float* __restrict__ emb,
                                                    float* __restrict__ enorm) {
    int wave = (blockIdx.x * blockDim.x + threadIdx.x) >> 6;
    int lane = threadIdx.x & 63;
    if (wave >= K_CODES) return;
    float v = emb[wave * DIM + lane];
    float s = v * v;
    #pragma unroll
    for (int m = 32; m >= 1; m >>= 1) s += __shfl_xor(s, m, 64);
    if (lane == 0) enorm[wave] = s;
}

// ---------------- K2: argmin + z_q + loss + scatter EMA ----------------
// 64 tokens per block, tiles of 128 codes, 256 threads, 4x8 micro-tile.
__global__ __launch_bounds__(256) void vq_main(const float* __restrict__ z,
                                               const float* __restrict__ emb,
                                               const float* __restrict__ enorm,
                                               float* __restrict__ zq_out,
                                               float* __restrict__ idx_out,
                                               float* __restrict__ cnt,
                                               float* __restrict__ new_ema,
                                               float* __restrict__ loss_sum) {
    __shared__ float z_s[DIM * 64];     // [d][t]  16 KB
    __shared__ float e_s[DIM * 128];    // [d][k]  32 KB (reused for reduction)
    __shared__ float enorm_s[128];
    __shared__ int   idx_s[64];

    const int tid = threadIdx.x;
    const int n0  = blockIdx.x * 64;                      // first token of tile
    const int zbase = (n0 >> 10) * CHW + (n0 & 1023);     // b*CHW + hw0

    // Stage z tile: global [c][hw contiguous] -> LDS [c][t], float4 coalesced.
    {
        int f4 = tid & 15, c0 = tid >> 4;
        #pragma unroll
        for (int r = 0; r < 4; ++r) {
            int c = c0 + 16 * r;
            float4 v = *(const float4*)(z + zbase + c * HWSZ + f4 * 4);
            *(float4*)(&z_s[c * 64 + f4 * 4]) = v;
        }
    }

    const int tx = tid & 15;   // code group (8 codes)
    const int ty = tid >> 4;   // token group (4 tokens)

    float minv[4];
    int   mini[4];
    #pragma unroll
    for (int i = 0; i < 4; ++i) { minv[i] = FLT_MAX; mini[i] = 0; }

    for (int kt = 0; kt < K_CODES / 128; ++kt) {
        __syncthreads();  // prior readers of e_s/enorm_s done (also covers z staging at kt=0)
        const int k0 = kt * 128;
        // Stage e tile transposed: each thread loads 8 float4 along d of one code row.
        {
            int k_local = tid >> 1, half = tid & 1;
            const float* src = emb + (k0 + k_local) * DIM + half * 32;
            #pragma unroll
            for (int j = 0; j < 8; ++j) {
                float4 v = *(const float4*)(src + j * 4);
                int d = half * 32 + j * 4;
                e_s[(d + 0) * 128 + k_local] = v.x;
                e_s[(d + 1) * 128 + k_local] = v.y;
                e_s[(d + 2) * 128 + k_local] = v.z;
                e_s[(d + 3) * 128 + k_local] = v.w;
            }
            if (tid < 128) enorm_s[tid] = enorm[k0 + tid];
        }
        __syncthreads();

        float acc[4][8];
        #pragma unroll
        for (int i = 0; i < 4; ++i)
            #pragma unroll
            for (int j = 0; j < 8; ++j) acc[i][j] = 0.f;

        #pragma unroll 8
        for (int d = 0; d < DIM; ++d) {
            float4 zv = *(const float4*)(&z_s[d * 64 + ty * 4]);
            float4 ea = *(const float4*)(&e_s[d * 128 + tx * 8]);
            float4 eb = *(const float4*)(&e_s[d * 128 + tx * 8 + 4]);
            float zr[4] = {zv.x, zv.y, zv.z, zv.w};
            float er[8] = {ea.x, ea.y, ea.z, ea.w, eb.x, eb.y, eb.z, eb.w};
            #pragma unroll
            for (int i = 0; i < 4; ++i)
                #pragma unroll
                for (int j = 0; j < 8; ++j) acc[i][j] = fmaf(zr[i], er[j], acc[i][j]);
        }

        // score = ||e||^2 - 2 z.e ; strict < keeps first index (k ascending per thread)
        #pragma unroll
        for (int j = 0; j < 8; ++j) {
            float en = enorm_s[tx * 8 + j];
            int k = k0 + tx * 8 + j;
            #pragma unroll
            for (int i = 0; i < 4; ++i) {
                float s = fmaf(-2.f, acc[i][j], en);
                if (s < minv[i]) { minv[i] = s; mini[i] = k; }
            }
        }
    }

    // Cross-thread (over tx) reduction via LDS overlaid on e_s.
    __syncthreads();
    float* red_val = e_s;                       // 1024 floats
    int*   red_idx = (int*)(e_s + 1024);        // 1024 ints
    #pragma unroll
    for (int i = 0; i < 4; ++i) {
        int t = ty * 4 + i;
        red_val[t * 16 + tx] = minv[i];
        red_idx[t * 16 + tx] = mini[i];
    }
    __syncthreads();
    if (tid < 64) {
        int base = tid * 16;
        float bv = red_val[base];
        int   bi = red_idx[base];
        #pragma unroll
        for (int x = 1; x < 16; ++x) {
            float v = red_val[base + x];
            int  ii = red_idx[base + x];
            if (v < bv || (v == bv && ii < bi)) { bv = v; bi = ii; }
        }
        idx_s[tid] = bi;
        idx_out[n0 + tid] = (float)bi;
        atomicAdd(&cnt[bi], 1.0f);
    }
    __syncthreads();

    // Epilogue: gather z_q, write z_q_st (NCHW), loss partial, EMA scatter.
    {
        int tloc = tid & 63, cg = tid >> 6;
        int n = n0 + tloc;
        int b = n >> 10, hw = n & 1023;
        int myidx = idx_s[tloc];
        const float* erow = emb + myidx * DIM;
        float* orow = zq_out + b * CHW + hw;
        float* nrow = new_ema + myidx * DIM;
        float lsum = 0.f;
        #pragma unroll
        for (int j = 0; j < 16; ++j) {
            int c = cg * 16 + j;
            float zq = erow[c];
            float zv = z_s[c * 64 + tloc];
            float dd = zq - zv;
            orow[c * HWSZ] = zv + dd;       // mimics z + (z_q - z)
            lsum += dd * dd;
            atomicAdd(&nrow[c], zv);
        }
        #pragma unroll
        for (int m = 32; m >= 1; m >>= 1) lsum += __shfl_xor(lsum, m, 64);
        if ((tid & 63) == 0) atomicAdd(loss_sum, lsum);
    }
}

// ---------------- K3: cs = decay*cluster_size + (1-decay)*cnt, and sum(cs) ----------------
__global__ __launch_bounds__(256) void cs_kernel(const float* __restrict__ cluster_size,
                                                 const float* __restrict__ cnt,
                                                 float* __restrict__ cs,
                                                 float* __restrict__ cs_sum) {
    int k = blockIdx.x * 256 + threadIdx.x;
    float v = 0.99f * cluster_size[k] + 0.01f * cnt[k];
    cs[k] = v;
    float s = v;
    #pragma unroll
    for (int m = 32; m >= 1; m >>= 1) s += __shfl_xor(s, m, 64);
    __shared__ float wsum[4];
    int lane = threadIdx.x & 63, wid = threadIdx.x >> 6;
    if (lane == 0) wsum[wid] = s;
    __syncthreads();
    if (threadIdx.x == 0) atomicAdd(cs_sum, wsum[0] + wsum[1] + wsum[2] + wsum[3]);
}

// ---------------- K4: finalize cs_norm, ema_w_out, emb_out, loss ----------------
__global__ __launch_bounds__(256) void final_kernel(const float* __restrict__ ema_w,
                                                    const float* __restrict__ cs,
                                                    const float* __restrict__ cs_sum,
                                                    const float* __restrict__ loss_sum,
                                                    float* __restrict__ csn_out,
                                                    float* __restrict__ emao_out,
                                                    float* __restrict__ embo_out,  // new_ema in, emb_out out
                                                    float* __restrict__ loss_out) {
    int g = blockIdx.x * 256 + threadIdx.x;   // 0..524287
    float denom = *cs_sum + (float)(K_CODES * 1e-5);
    int k = g >> 6;
    float csn = (cs[k] + 1e-5f) / denom;
    float ne = embo_out[g];                    // accumulated new_ema_w
    float eo = 0.99f * ema_w[g] + 0.01f * ne;
    emao_out[g] = eo;
    embo_out[g] = eo / csn;
    if (g < K_CODES) csn_out[g] = (cs[g] + 1e-5f) / denom;
    if (g == 0) *loss_out = 0.25f * (*loss_sum) * (1.0f / (float)NELEM);
}

extern "C" void kernel_launch(void* const* d_in, const int* in_sizes, int n_in,
                              void* d_out, int out_size, void* d_ws, size_t ws_size,
                              hipStream_t stream) {
    (void)in_sizes; (void)n_in; (void)out_size; (void)ws_size;
    const float* z      = (const float*)d_in[0];
    const float* emb    = (const float*)d_in[1];
    const float* ema_w  = (const float*)d_in[2];
    const float* csize  = (const float*)d_in[3];

    float* out      = (float*)d_out;
    float* zq_out   = out;
    float* loss_out = out + 2097152;
    float* idx_out  = out + 2097153;
    float* csn_out  = out + 2129921;   // cnt accumulator, then cs_norm
    float* emao_out = out + 2138113;
    float* embo_out = out + 2662401;   // new_ema accumulator, then emb_out

    float* ws       = (float*)d_ws;
    float* enorm    = ws;              // 8192
    float* cs       = ws + 8192;       // 8192
    float* cs_sum   = ws + 16384;      // 1
    float* loss_sum = ws + 16385;      // 1

    hipMemsetAsync(csn_out, 0, K_CODES * sizeof(float), stream);
    hipMemsetAsync(embo_out, 0, K_CODES * DIM * sizeof(float), stream);
    hipMemsetAsync(cs_sum, 0, 2 * sizeof(float), stream);

    enorm_kernel<<<K_CODES * 64 / 256, 256, 0, stream>>>(emb, enorm);
    vq_main<<<N_TOK / 64, 256, 0, stream>>>(z, emb, enorm, zq_out, idx_out,
                                            csn_out, embo_out, loss_sum);
    cs_kernel<<<K_CODES / 256, 256, 0, stream>>>(csize, csn_out, cs, cs_sum);
    final_kernel<<<K_CODES * DIM / 256, 256, 0, stream>>>(ema_w, cs, cs_sum, loss_sum,
                                                          csn_out, emao_out, embo_out, loss_out);
}